// Round 7
// baseline (128.364 us; speedup 1.0000x reference)
//
#include <hip/hip_runtime.h>

// FeaStConv x2, HEADS=1 => softmax==1 => layer = relu((segsum(h[src])@W)/deg + b).
// Pipeline (4 dispatches):
//   k_prep   : zero cnt[n]+ovf_cnt, repack W1 -> global pack (interleaved hi|lo
//              bf16 MFMA B-fragments, 32B per fragment-lane)
//   k_fill   : per-dst bucket build (CAP=16 atomic append; overflow -> (src,dst) list)
//   k_gdense : 1-wave blocks, 2 node-groups (32 nodes) per wave; fused neighbor
//              gather into A-fragments + 3-term bf16-split MFMA (xs@W1) +
//              relu/deg/b1 + W2 epilogue -> p[N,4]
//   k_out    : layer-2 gather of p + bias/relu -> out
// Overflow (deg>CAP) handled by in-kernel scan of the tiny overflow list.

#define TPB 256
#define CAP 16

typedef __attribute__((ext_vector_type(8))) short bf16x8;
typedef __attribute__((ext_vector_type(4))) float f32x4;

__device__ __forceinline__ void split_bf16(float f, ushort& hi, ushort& lo) {
    unsigned u = __float_as_uint(f);
    unsigned h = u >> 16;
    float fh = __uint_as_float(h << 16);
    float r = f - fh;                      // exact
    hi = (ushort)h;
    lo = (ushort)(__float_as_uint(r) >> 16);
}

// blocks [0, zb): zero cnt+ovf_cnt. blocks [zb, zb+7): W1 fragment repack.
__global__ void k_prep(int* __restrict__ cnt, int n1, int zb,
                       const float* __restrict__ W1, ushort* __restrict__ pack) {
    if ((int)blockIdx.x < zb) {
        int gid = blockIdx.x * TPB + threadIdx.x;
        if (gid < n1) cnt[gid] = 0;
    } else {
        int t = (blockIdx.x - zb) * TPB + threadIdx.x;   // 25*64 = 1600 frags
        if (t >= 25 * 64) return;
        int ct = t >> 6, l = t & 63;
        int kh = l >> 4, c = l & 15;
#pragma unroll
        for (int e = 0; e < 8; e++) {
            // B[k][col] fragment: k = 8*kh + e, col = ct*16 + c
            float f = W1[(8 * kh + e) * 400 + ct * 16 + c];
            ushort h, lo; split_bf16(f, h, lo);
            pack[t * 16 + e] = h;
            pack[t * 16 + 8 + e] = lo;
        }
    }
}

__global__ void k_fill(const int* __restrict__ src, const int* __restrict__ dst,
                       int* __restrict__ cnt, int* __restrict__ bucket,
                       int* __restrict__ ovf_cnt, int2* __restrict__ ovf_list, int E) {
    int e = blockIdx.x * TPB + threadIdx.x;
    if (e >= E) return;
    int d = dst[e];
    int s = src[e];
    int slot = atomicAdd(&cnt[d], 1);
    if (slot < CAP) bucket[(size_t)d * CAP + slot] = s;
    else { int pos = atomicAdd(ovf_cnt, 1); ovf_list[pos] = make_int2(s, d); }
}

// One wave per block; wave handles 32 nodes as 2 groups of 16.
// Lane l: node-in-group r = l&15, channel octet kh = l>>4.
__global__ __launch_bounds__(64) void k_gdense(
    const float* __restrict__ x, const int* __restrict__ cnt,
    const int* __restrict__ bucket, const int* __restrict__ ovf_cnt,
    const int2* __restrict__ ovf_list, const ushort* __restrict__ pack,
    const float* __restrict__ b1, const float* __restrict__ W2,
    float* __restrict__ p, int n) {
    int l = threadIdx.x;
    int r = l & 15, kh = l >> 4;
    int base = blockIdx.x * 32;

    bf16x8 ah[2], al[2];
    float invd_q[2][4];

#pragma unroll
    for (int g = 0; g < 2; g++) {
        int node = base + g * 16 + r; if (node > n - 1) node = n - 1;
        int m = cnt[node];
        int mb = m < CAP ? m : CAP;

        // self term
        const float4* xp = (const float4*)(x + (size_t)node * 32 + kh * 8);
        float4 s0 = xp[0], s1 = xp[1];
        float acc[8] = {s0.x, s0.y, s0.z, s0.w, s1.x, s1.y, s1.z, s1.w};

        const int4* bkt = (const int4*)(bucket + (size_t)node * CAP);
#pragma unroll
        for (int c4 = 0; c4 < CAP / 4; c4++) {
            if (4 * c4 < mb) {
                int4 b = bkt[c4];
                int base_s = 4 * c4;
                int ids[4] = {b.x, b.y, b.z, b.w};
#pragma unroll
                for (int j = 0; j < 4; j++) {
                    if (base_s + j < mb) {
                        const float4* vp = (const float4*)(x + (size_t)ids[j] * 32 + kh * 8);
                        float4 v0 = vp[0], v1 = vp[1];
                        acc[0] += v0.x; acc[1] += v0.y; acc[2] += v0.z; acc[3] += v0.w;
                        acc[4] += v1.x; acc[5] += v1.y; acc[6] += v1.z; acc[7] += v1.w;
                    }
                }
            }
        }
        if (m > CAP) {                       // rare; exec-masked
            int L = ovf_cnt[0];
            for (int j = 0; j < L; j++) {
                int2 sd = ovf_list[j];
                if (sd.y == node) {
                    const float4* vp = (const float4*)(x + (size_t)sd.x * 32 + kh * 8);
                    float4 v0 = vp[0], v1 = vp[1];
                    acc[0] += v0.x; acc[1] += v0.y; acc[2] += v0.z; acc[3] += v0.w;
                    acc[4] += v1.x; acc[5] += v1.y; acc[6] += v1.z; acc[7] += v1.w;
                }
            }
        }

#pragma unroll
        for (int e = 0; e < 8; e++) {
            ushort h, lo; split_bf16(acc[e], h, lo);
            ah[g][e] = (short)h; al[g][e] = (short)lo;
        }

#pragma unroll
        for (int q = 0; q < 4; q++) {
            int nq = base + g * 16 + kh * 4 + q; if (nq > n - 1) nq = n - 1;
            invd_q[g][q] = __builtin_amdgcn_rcpf((float)(cnt[nq] + 1));
        }
    }

    float pacc[2][4][4];
#pragma unroll
    for (int g = 0; g < 2; g++)
#pragma unroll
        for (int q = 0; q < 4; q++)
#pragma unroll
            for (int o = 0; o < 4; o++) pacc[g][q][o] = 0.f;

    for (int ct = 0; ct < 25; ct++) {
        const ushort* pk = pack + (((size_t)ct * 64 + l) << 4);
        bf16x8 bh = *(const bf16x8*)pk;
        bf16x8 bl = *(const bf16x8*)(pk + 8);
        float b1v = b1[ct * 16 + r];
        const float4 w2v = *(const float4*)(W2 + (size_t)(ct * 16 + r) * 4);
#pragma unroll
        for (int g = 0; g < 2; g++) {
            f32x4 c = {0.f, 0.f, 0.f, 0.f};
            c = __builtin_amdgcn_mfma_f32_16x16x32_bf16(ah[g], bh, c, 0, 0, 0);
            c = __builtin_amdgcn_mfma_f32_16x16x32_bf16(al[g], bh, c, 0, 0, 0);
            c = __builtin_amdgcn_mfma_f32_16x16x32_bf16(ah[g], bl, c, 0, 0, 0);
#pragma unroll
            for (int q = 0; q < 4; q++) {
                float h = fmaxf(fmaf(c[q], invd_q[g][q], b1v), 0.f);
                pacc[g][q][0] = fmaf(h, w2v.x, pacc[g][q][0]);
                pacc[g][q][1] = fmaf(h, w2v.y, pacc[g][q][1]);
                pacc[g][q][2] = fmaf(h, w2v.z, pacc[g][q][2]);
                pacc[g][q][3] = fmaf(h, w2v.w, pacc[g][q][3]);
            }
        }
    }
    // reduce over r (lane bits 0..3)
#pragma unroll
    for (int mask = 1; mask <= 8; mask <<= 1)
#pragma unroll
        for (int g = 0; g < 2; g++)
#pragma unroll
            for (int q = 0; q < 4; q++)
#pragma unroll
                for (int o = 0; o < 4; o++)
                    pacc[g][q][o] += __shfl_xor(pacc[g][q][o], mask, 64);

    if (r < 4) {
#pragma unroll
        for (int g = 0; g < 2; g++) {
            int nd = base + g * 16 + kh * 4 + r;
            if (nd < n)
                *(float4*)(p + (size_t)nd * 4) =
                    make_float4(pacc[g][r][0], pacc[g][r][1], pacc[g][r][2], pacc[g][r][3]);
        }
    }
}

// layer-2: agg = p[node] + sum_nb p[nb]; out = relu(agg/deg + b2). 1 thread per (node,c).
__global__ void k_out(const float* __restrict__ p, const int* __restrict__ cnt,
                      const int* __restrict__ bucket, const int* __restrict__ ovf_cnt,
                      const int2* __restrict__ ovf_list,
                      const float* __restrict__ b2, float* __restrict__ out, int n) {
    int gid = blockIdx.x * blockDim.x + threadIdx.x;
    int node = gid >> 2, c = gid & 3;
    if (node >= n) return;
    int m = cnt[node];
    int mb = m < CAP ? m : CAP;
    float acc = p[(size_t)node * 4 + c];
    const int4* bkt = (const int4*)(bucket + (size_t)node * CAP);
#pragma unroll
    for (int c4 = 0; c4 < CAP / 4; c4++) {
        if (4 * c4 < mb) {
            int4 b = bkt[c4];
            int base_s = 4 * c4;
            int ids[4] = {b.x, b.y, b.z, b.w};
#pragma unroll
            for (int j = 0; j < 4; j++) {
                if (base_s + j < mb) acc += p[(size_t)ids[j] * 4 + c];
            }
        }
    }
    if (m > CAP) {
        int L = ovf_cnt[0];
        for (int j = 0; j < L; j++) {
            int2 sd = ovf_list[j];
            if (sd.y == node) acc += p[(size_t)sd.x * 4 + c];
        }
    }
    out[gid] = fmaxf(fmaf(acc, __builtin_amdgcn_rcpf((float)(m + 1)), b2[c]), 0.f);
}

static inline size_t align4i(size_t v) { return (v + 3) & ~(size_t)3; }

extern "C" void kernel_launch(void* const* d_in, const int* in_sizes, int n_in,
                              void* d_out, int out_size, void* d_ws, size_t ws_size,
                              hipStream_t stream) {
    const float* x  = (const float*)d_in[0];
    const int*   ei = (const int*)d_in[1];
    const float* W1 = (const float*)d_in[2];
    const float* b1 = (const float*)d_in[5];
    const float* W2 = (const float*)d_in[6];
    const float* b2 = (const float*)d_in[9];

    int n = in_sizes[0] / 32;
    int E = in_sizes[1] / 2;
    const int* src = ei;
    const int* dst = ei + E;

    // workspace layout (int units, 16B-aligned sections)
    int* wsi = (int*)d_ws;
    size_t off = 0;
    int* cnt      = wsi + off; off += n;                  // n
    int* ovf_cnt  = wsi + off; off += 1;                  // zeroed with cnt
    size_t off_ovf = align4i(off);
    int2* ovf_list = (int2*)(wsi + off_ovf); off = off_ovf + 2 * (size_t)E;
    size_t off_b  = align4i(off);
    int* bucket   = wsi + off_b;  off = off_b + (size_t)n * CAP;
    size_t off_p  = align4i(off);
    float* p      = (float*)(wsi + off_p); off = off_p + (size_t)n * 4;
    size_t off_pk = align4i(off);
    ushort* pack  = (ushort*)(wsi + off_pk);              // 25600 ushorts
    float* out    = (float*)d_out;

    int zb = (n + 1 + TPB - 1) / TPB;
    k_prep<<<zb + 7, TPB, 0, stream>>>(cnt, n + 1, zb, W1, pack);
    k_fill<<<(E + TPB - 1) / TPB, TPB, 0, stream>>>(src, dst, cnt, bucket,
                                                    ovf_cnt, ovf_list, E);
    k_gdense<<<(n + 31) / 32, 64, 0, stream>>>(x, cnt, bucket, ovf_cnt, ovf_list,
                                               pack, b1, W2, p, n);
    k_out<<<((size_t)n * 4 + TPB - 1) / TPB, TPB, 0, stream>>>(p, cnt, bucket,
                                                               ovf_cnt, ovf_list,
                                                               b2, out, n);
}

// Round 8
// 101.615 us; speedup vs baseline: 1.2632x; 1.2632x over previous
//
#include <hip/hip_runtime.h>

// FeaStConv x2, HEADS=1 => softmax==1 => layer = relu((segsum(h[src])@W)/deg + b).
// 5 dispatches, each shaped for its bottleneck:
//   k_prep   : zero cnt+ovf_cnt, repack W1 -> global pack (interleaved hi|lo bf16
//              MFMA B-fragments, 32B/fragment-lane)
//   k_fill   : per-dst bucket build (CAP=16 atomic append; overflow -> (src,dst))
//   k_gather : WAVE PER NODE (50k waves, max TLP) neighbor-sum -> xs[N,32], invd[N]
//   k_dense  : 16 nodes/wave MFMA; pack bulk-copied to LDS per block; 3-term
//              bf16-split (xs@W1) + relu/deg/b1 + W2 epilogue -> p[N,4]
//   k_out    : WAVE PER NODE layer-2 gather of p + bias/relu -> out
// Overflow (deg>CAP) handled by in-kernel scan of the tiny overflow list.

#define TPB 256
#define CAP 16

typedef __attribute__((ext_vector_type(8))) short bf16x8;
typedef __attribute__((ext_vector_type(4))) float f32x4;

__device__ __forceinline__ void split_bf16(float f, ushort& hi, ushort& lo) {
    unsigned u = __float_as_uint(f);
    unsigned h = u >> 16;
    float fh = __uint_as_float(h << 16);
    float r = f - fh;                      // exact
    hi = (ushort)h;
    lo = (ushort)(__float_as_uint(r) >> 16);
}

// blocks [0, zb): zero cnt+ovf_cnt. blocks [zb, zb+7): W1 fragment repack.
__global__ void k_prep(int* __restrict__ cnt, int n1, int zb,
                       const float* __restrict__ W1, ushort* __restrict__ pack) {
    if ((int)blockIdx.x < zb) {
        int gid = blockIdx.x * TPB + threadIdx.x;
        if (gid < n1) cnt[gid] = 0;
    } else {
        int t = (blockIdx.x - zb) * TPB + threadIdx.x;   // 25*64 = 1600 frags
        if (t >= 25 * 64) return;
        int ct = t >> 6, l = t & 63;
        int kh = l >> 4, c = l & 15;
#pragma unroll
        for (int e = 0; e < 8; e++) {
            // B[k][col] fragment: k = 8*kh + e, col = ct*16 + c
            float f = W1[(8 * kh + e) * 400 + ct * 16 + c];
            ushort h, lo; split_bf16(f, h, lo);
            pack[t * 16 + e] = h;
            pack[t * 16 + 8 + e] = lo;
        }
    }
}

__global__ void k_fill(const int* __restrict__ src, const int* __restrict__ dst,
                       int* __restrict__ cnt, int* __restrict__ bucket,
                       int* __restrict__ ovf_cnt, int2* __restrict__ ovf_list, int E) {
    int e = blockIdx.x * TPB + threadIdx.x;
    if (e >= E) return;
    int d = dst[e];
    int s = src[e];
    int slot = atomicAdd(&cnt[d], 1);
    if (slot < CAP) bucket[(size_t)d * CAP + slot] = s;
    else { int pos = atomicAdd(ovf_cnt, 1); ovf_list[pos] = make_int2(s, d); }
}

// Wave per node. Lane l: channel ch = l&31, slot-half h = l>>5.
__global__ __launch_bounds__(256) void k_gather(
    const float* __restrict__ x, const int* __restrict__ cnt,
    const int* __restrict__ bucket, const int* __restrict__ ovf_cnt,
    const int2* __restrict__ ovf_list,
    float* __restrict__ xs, float* __restrict__ invd, int n) {
    int node = blockIdx.x * 4 + (threadIdx.x >> 6);
    if (node >= n) return;
    int l = threadIdx.x & 63;
    int ch = l & 31, h = l >> 5;
    int m = cnt[node];
    int mb = m < CAP ? m : CAP;

    const int4* bkt = (const int4*)(bucket + (size_t)node * CAP);
    float acc = 0.f;
#pragma unroll
    for (int cc = 0; cc < 2; cc++) {            // chunk = 4 slots
        int s0 = 8 * h + 4 * cc;
        if (s0 < mb) {
            int4 b = bkt[2 * h + cc];
            int idq[4] = {b.x, b.y, b.z, b.w};
#pragma unroll
            for (int j = 0; j < 4; j++) {
                int id = (s0 + j < mb) ? idq[j] : node;
                float v = x[(size_t)id * 32 + ch];
                acc += (s0 + j < mb) ? v : 0.f;
            }
        }
    }
    if (h == 0) acc += x[(size_t)node * 32 + ch];          // self-loop
    else if (m > CAP) {                                    // rare overflow (h==1 lanes)
        int L = ovf_cnt[0];
        for (int j = 0; j < L; j++) {
            int2 sd = ovf_list[j];
            if (sd.y == node) acc += x[(size_t)sd.x * 32 + ch];
        }
    }
    acc += __shfl_xor(acc, 32);
    if (h == 0) {
        xs[(size_t)node * 32 + ch] = acc;
        if (ch == 0) invd[node] = __builtin_amdgcn_rcpf((float)(m + 1));
    }
}

// 4 waves/block, wave = 16 nodes. Lane l: node r = l&15, channel octet kh = l>>4.
__global__ __launch_bounds__(256) void k_dense(
    const float* __restrict__ xs, const float* __restrict__ invd,
    const ushort* __restrict__ pack, const float* __restrict__ b1,
    const float* __restrict__ W2, float* __restrict__ p, int n) {
    __shared__ __align__(16) ushort sPack[25600];   // 51.2 KB, contiguous copy
    {
        const uint4* g4 = (const uint4*)pack;
        uint4* s4 = (uint4*)sPack;
        for (int i = threadIdx.x; i < 3200; i += TPB) s4[i] = g4[i];
    }

    int wid = threadIdx.x >> 6, l = threadIdx.x & 63;
    int r = l & 15, kh = l >> 4;
    int base = (blockIdx.x * 4 + wid) * 16;
    bool active = base < n;                          // wave-uniform

    bf16x8 a_hi, a_lo;
    float invd_q[4];
    if (active) {
        int node = base + r; if (node > n - 1) node = n - 1;
        const float4* xp = (const float4*)(xs + (size_t)node * 32 + kh * 8);
        float4 v0 = xp[0], v1 = xp[1];
        float xv[8] = {v0.x, v0.y, v0.z, v0.w, v1.x, v1.y, v1.z, v1.w};
#pragma unroll
        for (int e = 0; e < 8; e++) {
            ushort hi, lo; split_bf16(xv[e], hi, lo);
            a_hi[e] = (short)hi; a_lo[e] = (short)lo;
        }
        float iv = invd[node];                       // lane r holds invd[base+r]
#pragma unroll
        for (int q = 0; q < 4; q++)
            invd_q[q] = __shfl(iv, (l & 48) + kh * 4 + q, 64);
    }
    __syncthreads();
    if (!active) return;

    float pacc[4][4];
#pragma unroll
    for (int q = 0; q < 4; q++)
#pragma unroll
        for (int o = 0; o < 4; o++) pacc[q][o] = 0.f;

#pragma unroll 5
    for (int ct = 0; ct < 25; ct++) {
        const ushort* pk = sPack + ((ct * 64 + l) << 4);
        bf16x8 bh = *(const bf16x8*)pk;
        bf16x8 bl = *(const bf16x8*)(pk + 8);
        f32x4 c = {0.f, 0.f, 0.f, 0.f};
        c = __builtin_amdgcn_mfma_f32_16x16x32_bf16(a_hi, bh, c, 0, 0, 0);
        c = __builtin_amdgcn_mfma_f32_16x16x32_bf16(a_lo, bh, c, 0, 0, 0);
        c = __builtin_amdgcn_mfma_f32_16x16x32_bf16(a_hi, bl, c, 0, 0, 0);
        float b1v = b1[ct * 16 + r];
        const float4 w2v = *(const float4*)(W2 + (size_t)(ct * 16 + r) * 4);
#pragma unroll
        for (int q = 0; q < 4; q++) {
            float hq = fmaxf(fmaf(c[q], invd_q[q], b1v), 0.f);
            pacc[q][0] = fmaf(hq, w2v.x, pacc[q][0]);
            pacc[q][1] = fmaf(hq, w2v.y, pacc[q][1]);
            pacc[q][2] = fmaf(hq, w2v.z, pacc[q][2]);
            pacc[q][3] = fmaf(hq, w2v.w, pacc[q][3]);
        }
    }
    // reduce over r (lane bits 0..3)
#pragma unroll
    for (int mask = 1; mask <= 8; mask <<= 1)
#pragma unroll
        for (int q = 0; q < 4; q++)
#pragma unroll
            for (int o = 0; o < 4; o++)
                pacc[q][o] += __shfl_xor(pacc[q][o], mask, 64);

    if (r < 4) {
        int nd = base + kh * 4 + r;
        if (nd < n)
            *(float4*)(p + (size_t)nd * 4) =
                make_float4(pacc[r][0], pacc[r][1], pacc[r][2], pacc[r][3]);
    }
}

// Wave per node. Lane l: slot = l>>2 (0..15), out-channel c = l&3.
__global__ __launch_bounds__(256) void k_out(
    const float* __restrict__ p, const int* __restrict__ cnt,
    const int* __restrict__ bucket, const int* __restrict__ ovf_cnt,
    const int2* __restrict__ ovf_list,
    const float* __restrict__ b2, float* __restrict__ out, int n) {
    int node = blockIdx.x * 4 + (threadIdx.x >> 6);
    if (node >= n) return;
    int l = threadIdx.x & 63;
    int slot = l >> 2, c = l & 3;
    int m = cnt[node];
    int mb = m < CAP ? m : CAP;

    int id = (slot < mb) ? bucket[(size_t)node * CAP + slot] : node;
    float acc = (slot < mb) ? p[(size_t)id * 4 + c] : 0.f;
    if (slot == 0) acc += p[(size_t)node * 4 + c];          // self-loop
    if (m > CAP) {                                          // wave-uniform branch
        int L = ovf_cnt[0];
        for (int j = slot; j < L; j += 16) {
            int2 sd = ovf_list[j];
            if (sd.y == node) acc += p[(size_t)sd.x * 4 + c];
        }
    }
    acc += __shfl_xor(acc, 4);
    acc += __shfl_xor(acc, 8);
    acc += __shfl_xor(acc, 16);
    acc += __shfl_xor(acc, 32);
    if (l < 4)
        out[(size_t)node * 4 + l] =
            fmaxf(fmaf(acc, __builtin_amdgcn_rcpf((float)(m + 1)), b2[l]), 0.f);
}

static inline size_t align4i(size_t v) { return (v + 3) & ~(size_t)3; }

extern "C" void kernel_launch(void* const* d_in, const int* in_sizes, int n_in,
                              void* d_out, int out_size, void* d_ws, size_t ws_size,
                              hipStream_t stream) {
    const float* x  = (const float*)d_in[0];
    const int*   ei = (const int*)d_in[1];
    const float* W1 = (const float*)d_in[2];
    const float* b1 = (const float*)d_in[5];
    const float* W2 = (const float*)d_in[6];
    const float* b2 = (const float*)d_in[9];

    int n = in_sizes[0] / 32;
    int E = in_sizes[1] / 2;
    const int* src = ei;
    const int* dst = ei + E;

    // workspace layout (int units, 16B-aligned sections)
    int* wsi = (int*)d_ws;
    size_t off = 0;
    int* cnt      = wsi + off; off += n;                  // n
    int* ovf_cnt  = wsi + off; off += 1;                  // zeroed with cnt
    size_t off_ovf = align4i(off);
    int2* ovf_list = (int2*)(wsi + off_ovf); off = off_ovf + 2 * (size_t)E;
    size_t off_b  = align4i(off);
    int* bucket   = wsi + off_b;  off = off_b + (size_t)n * CAP;
    size_t off_xs = align4i(off);
    float* xs     = (float*)(wsi + off_xs); off = off_xs + (size_t)n * 32;
    float* invd   = (float*)(wsi + off);    off += n;
    size_t off_p  = align4i(off);
    float* p      = (float*)(wsi + off_p);  off = off_p + (size_t)n * 4;
    size_t off_pk = align4i(off);
    ushort* pack  = (ushort*)(wsi + off_pk);              // 25600 ushorts
    float* out    = (float*)d_out;

    int zb = (n + 1 + TPB - 1) / TPB;
    k_prep<<<zb + 7, TPB, 0, stream>>>(cnt, n + 1, zb, W1, pack);
    k_fill<<<(E + TPB - 1) / TPB, TPB, 0, stream>>>(src, dst, cnt, bucket,
                                                    ovf_cnt, ovf_list, E);
    k_gather<<<(n + 3) / 4, TPB, 0, stream>>>(x, cnt, bucket, ovf_cnt, ovf_list,
                                              xs, invd, n);
    int tiles = (n + 15) / 16;
    k_dense<<<(tiles + 3) / 4, TPB, 0, stream>>>(xs, invd, pack, b1, W2, p, n);
    k_out<<<(n + 3) / 4, TPB, 0, stream>>>(p, cnt, bucket, ovf_cnt, ovf_list,
                                           b2, out, n);
}

// Round 9
// 92.997 us; speedup vs baseline: 1.3803x; 1.0927x over previous
//
#include <hip/hip_runtime.h>

// FeaStConv x2, HEADS=1 => softmax==1 => layer = relu((segsum(h[src])@W)/deg + b).
// dur_us model: own kernels + ~40us harness d_ws poison fill (immovable).
// 5 dispatches:
//   k_prep   : zero cnt+ovf_cnt, repack W1 -> packHi/packLo (bf16 MFMA B-frags)
//   k_fill   : per-dst bucket build, CAP-15 (slot 15 reserved; overflow list)
//   k_gather : wave per node, SLOT-PARALLEL lanes (s=l>>2, q=l&3): 1 bucket dword
//              + 2 indep float4 loads per lane; self via s==mb lane -> xs, invd
//   k_dense  : grid-stride 512 blocks; pack bulk-copied to LDS per block;
//              3-term bf16-split MFMA (xs@W1) + relu/deg/b1 + W2 epilogue -> p
//   k_out    : wave per node slot-parallel layer-2 gather + bias/relu -> out

#define TPB 256
#define DGRID 512

typedef __attribute__((ext_vector_type(8))) short bf16x8;
typedef __attribute__((ext_vector_type(4))) float f32x4;

__device__ __forceinline__ void split_bf16(float f, ushort& hi, ushort& lo) {
    unsigned u = __float_as_uint(f);
    unsigned h = u >> 16;
    float fh = __uint_as_float(h << 16);
    float r = f - fh;                      // exact
    hi = (ushort)h;
    lo = (ushort)(__float_as_uint(r) >> 16);
}

// blocks [0, zb): zero cnt+ovf_cnt. blocks [zb, zb+7): W1 fragment repack.
__global__ void k_prep(int* __restrict__ cnt, int n1, int zb,
                       const float* __restrict__ W1,
                       ushort* __restrict__ packHi, ushort* __restrict__ packLo) {
    if ((int)blockIdx.x < zb) {
        int gid = blockIdx.x * TPB + threadIdx.x;
        if (gid < n1) cnt[gid] = 0;
    } else {
        int t = (blockIdx.x - zb) * TPB + threadIdx.x;   // 25*64 = 1600 frags
        if (t >= 25 * 64) return;
        int ct = t >> 6, l = t & 63;
        int kh = l >> 4, c = l & 15;
#pragma unroll
        for (int e = 0; e < 8; e++) {
            // B[k][col] fragment: k = 8*kh + e, col = ct*16 + c
            float f = W1[(8 * kh + e) * 400 + ct * 16 + c];
            ushort h, lo; split_bf16(f, h, lo);
            packHi[t * 8 + e] = h;
            packLo[t * 8 + e] = lo;
        }
    }
}

// CAP-15: slots 0..14 in bucket (stride 16), slot>=15 -> overflow list.
__global__ void k_fill(const int* __restrict__ src, const int* __restrict__ dst,
                       int* __restrict__ cnt, int* __restrict__ bucket,
                       int* __restrict__ ovf_cnt, int2* __restrict__ ovf_list, int E) {
    int e = blockIdx.x * TPB + threadIdx.x;
    if (e >= E) return;
    int d = dst[e];
    int s = src[e];
    int slot = atomicAdd(&cnt[d], 1);
    if (slot < 15) bucket[(size_t)d * 16 + slot] = s;
    else { int pos = atomicAdd(ovf_cnt, 1); ovf_list[pos] = make_int2(s, d); }
}

// Wave per node. Lane l: slot s = l>>2 (0..15), quarter q = l&3 (8 channels).
// id = s<mb ? bucket : node (s==mb lane adds the self-loop row).
__global__ __launch_bounds__(256) void k_gather(
    const float* __restrict__ x, const int* __restrict__ cnt,
    const int* __restrict__ bucket, const int* __restrict__ ovf_cnt,
    const int2* __restrict__ ovf_list,
    float* __restrict__ xs, float* __restrict__ invd, int n) {
    int node = blockIdx.x * 4 + (threadIdx.x >> 6);
    if (node >= n) return;
    int l = threadIdx.x & 63;
    int s = l >> 2, q = l & 3;
    int m = cnt[node];
    int mb = m < 15 ? m : 15;

    int bkt = bucket[(size_t)node * 16 + s];
    int id = (s < mb) ? bkt : node;
    bool inc = (s <= mb);
    const float4* row = (const float4*)(x + (size_t)id * 32 + q * 8);
    float4 va = row[0], vb = row[1];
    float acc[8];
    acc[0] = inc ? va.x : 0.f; acc[1] = inc ? va.y : 0.f;
    acc[2] = inc ? va.z : 0.f; acc[3] = inc ? va.w : 0.f;
    acc[4] = inc ? vb.x : 0.f; acc[5] = inc ? vb.y : 0.f;
    acc[6] = inc ? vb.z : 0.f; acc[7] = inc ? vb.w : 0.f;

    if (m > 15) {                          // wave-uniform, rare
        int L = ovf_cnt[0];
        for (int j = s; j < L; j += 16) {
            int2 sd = ovf_list[j];
            if (sd.y == node) {
                const float4* r2 = (const float4*)(x + (size_t)sd.x * 32 + q * 8);
                float4 wa = r2[0], wb = r2[1];
                acc[0] += wa.x; acc[1] += wa.y; acc[2] += wa.z; acc[3] += wa.w;
                acc[4] += wb.x; acc[5] += wb.y; acc[6] += wb.z; acc[7] += wb.w;
            }
        }
    }
#pragma unroll
    for (int mask = 4; mask <= 32; mask <<= 1)
#pragma unroll
        for (int i = 0; i < 8; i++) acc[i] += __shfl_xor(acc[i], mask, 64);

    if (s == 0) {
        float4* dstp = (float4*)(xs + (size_t)node * 32 + q * 8);
        dstp[0] = make_float4(acc[0], acc[1], acc[2], acc[3]);
        dstp[1] = make_float4(acc[4], acc[5], acc[6], acc[7]);
        if (q == 0) invd[node] = __builtin_amdgcn_rcpf((float)(m + 1));
    }
}

// Grid-stride MFMA dense. 4 waves/block, wave-tile = 16 nodes.
// Pack bulk-copied (contiguous uint4) into LDS once per block.
__global__ __launch_bounds__(256) void k_dense(
    const float* __restrict__ xs, const float* __restrict__ invd,
    const ushort* __restrict__ packHi, const ushort* __restrict__ packLo,
    const float* __restrict__ b1, const float* __restrict__ W2,
    float* __restrict__ p, int n) {
    __shared__ __align__(16) ushort sHi[12800];   // 25.6 KB
    __shared__ __align__(16) ushort sLo[12800];   // 25.6 KB
    __shared__ __align__(16) float sW2[1600];     // 6.4 KB
    __shared__ float sb1[400];                    // 1.6 KB
    {
        const uint4* gh = (const uint4*)packHi;
        const uint4* gl = (const uint4*)packLo;
        uint4* sh = (uint4*)sHi;
        uint4* sl = (uint4*)sLo;
        for (int i = threadIdx.x; i < 1600; i += TPB) { sh[i] = gh[i]; sl[i] = gl[i]; }
        for (int i = threadIdx.x; i < 1600; i += TPB) sW2[i] = W2[i];
        for (int i = threadIdx.x; i < 400; i += TPB) sb1[i] = b1[i];
    }
    __syncthreads();

    int wid = threadIdx.x >> 6, l = threadIdx.x & 63;
    int r = l & 15, kh = l >> 4;
    int ntile = (n + 15) >> 4;

    for (int tile = blockIdx.x * 4 + wid; tile < ntile; tile += DGRID * 4) {
        int base = tile * 16;
        int node = base + r; if (node > n - 1) node = n - 1;

        const float4* xp = (const float4*)(xs + (size_t)node * 32 + kh * 8);
        float4 v0 = xp[0], v1 = xp[1];
        float xv[8] = {v0.x, v0.y, v0.z, v0.w, v1.x, v1.y, v1.z, v1.w};
        bf16x8 a_hi, a_lo;
#pragma unroll
        for (int e = 0; e < 8; e++) {
            ushort hi, lo; split_bf16(xv[e], hi, lo);
            a_hi[e] = (short)hi; a_lo[e] = (short)lo;
        }
        float iv = invd[node];                       // lane r holds invd[base+r]
        float invd_q[4];
#pragma unroll
        for (int q = 0; q < 4; q++)
            invd_q[q] = __shfl(iv, (l & 48) + kh * 4 + q, 64);

        float pacc[4][4];
#pragma unroll
        for (int q = 0; q < 4; q++)
#pragma unroll
            for (int o = 0; o < 4; o++) pacc[q][o] = 0.f;

#pragma unroll 5
        for (int ct = 0; ct < 25; ct++) {
            bf16x8 bh = *(const bf16x8*)(sHi + ((ct * 64 + l) << 3));
            bf16x8 bl = *(const bf16x8*)(sLo + ((ct * 64 + l) << 3));
            f32x4 c = {0.f, 0.f, 0.f, 0.f};
            c = __builtin_amdgcn_mfma_f32_16x16x32_bf16(a_hi, bh, c, 0, 0, 0);
            c = __builtin_amdgcn_mfma_f32_16x16x32_bf16(a_lo, bh, c, 0, 0, 0);
            c = __builtin_amdgcn_mfma_f32_16x16x32_bf16(a_hi, bl, c, 0, 0, 0);
            float b1v = sb1[ct * 16 + r];
            const float4 w2v = *(const float4*)(&sW2[(ct * 16 + r) * 4]);
#pragma unroll
            for (int q = 0; q < 4; q++) {
                float hq = fmaxf(fmaf(c[q], invd_q[q], b1v), 0.f);
                pacc[q][0] = fmaf(hq, w2v.x, pacc[q][0]);
                pacc[q][1] = fmaf(hq, w2v.y, pacc[q][1]);
                pacc[q][2] = fmaf(hq, w2v.z, pacc[q][2]);
                pacc[q][3] = fmaf(hq, w2v.w, pacc[q][3]);
            }
        }
        // reduce over r (lane bits 0..3)
#pragma unroll
        for (int mask = 1; mask <= 8; mask <<= 1)
#pragma unroll
            for (int q = 0; q < 4; q++)
#pragma unroll
                for (int o = 0; o < 4; o++)
                    pacc[q][o] += __shfl_xor(pacc[q][o], mask, 64);

        if (r < 4) {
            int nd = base + kh * 4 + r;
            if (nd < n)
                *(float4*)(p + (size_t)nd * 4) =
                    make_float4(pacc[r][0], pacc[r][1], pacc[r][2], pacc[r][3]);
        }
    }
}

// Wave per node. Lane l: slot s = l>>2, out-channel c = l&3. Self via s==mb.
__global__ __launch_bounds__(256) void k_out(
    const float* __restrict__ p, const int* __restrict__ cnt,
    const int* __restrict__ bucket, const int* __restrict__ ovf_cnt,
    const int2* __restrict__ ovf_list,
    const float* __restrict__ b2, float* __restrict__ out, int n) {
    int node = blockIdx.x * 4 + (threadIdx.x >> 6);
    if (node >= n) return;
    int l = threadIdx.x & 63;
    int s = l >> 2, c = l & 3;
    int m = cnt[node];
    int mb = m < 15 ? m : 15;

    int bkt = bucket[(size_t)node * 16 + s];
    int id = (s < mb) ? bkt : node;
    float acc = (s <= mb) ? p[(size_t)id * 4 + c] : 0.f;
    if (m > 15) {                                           // wave-uniform, rare
        int L = ovf_cnt[0];
        for (int j = s; j < L; j += 16) {
            int2 sd = ovf_list[j];
            if (sd.y == node) acc += p[(size_t)sd.x * 4 + c];
        }
    }
    acc += __shfl_xor(acc, 4, 64);
    acc += __shfl_xor(acc, 8, 64);
    acc += __shfl_xor(acc, 16, 64);
    acc += __shfl_xor(acc, 32, 64);
    if (l < 4)
        out[(size_t)node * 4 + l] =
            fmaxf(fmaf(acc, __builtin_amdgcn_rcpf((float)(m + 1)), b2[l]), 0.f);
}

static inline size_t align4i(size_t v) { return (v + 3) & ~(size_t)3; }

extern "C" void kernel_launch(void* const* d_in, const int* in_sizes, int n_in,
                              void* d_out, int out_size, void* d_ws, size_t ws_size,
                              hipStream_t stream) {
    const float* x  = (const float*)d_in[0];
    const int*   ei = (const int*)d_in[1];
    const float* W1 = (const float*)d_in[2];
    const float* b1 = (const float*)d_in[5];
    const float* W2 = (const float*)d_in[6];
    const float* b2 = (const float*)d_in[9];

    int n = in_sizes[0] / 32;
    int E = in_sizes[1] / 2;
    const int* src = ei;
    const int* dst = ei + E;

    // workspace layout (int units, 16B-aligned sections)
    int* wsi = (int*)d_ws;
    size_t off = 0;
    int* cnt      = wsi + off; off += n;                  // n
    int* ovf_cnt  = wsi + off; off += 1;                  // zeroed with cnt
    size_t off_ovf = align4i(off);
    int2* ovf_list = (int2*)(wsi + off_ovf); off = off_ovf + 2 * (size_t)E;
    size_t off_b  = align4i(off);
    int* bucket   = wsi + off_b;  off = off_b + (size_t)n * 16;
    size_t off_xs = align4i(off);
    float* xs     = (float*)(wsi + off_xs); off = off_xs + (size_t)n * 32;
    float* invd   = (float*)(wsi + off);    off += n;
    size_t off_p  = align4i(off);
    float* p      = (float*)(wsi + off_p);  off = off_p + (size_t)n * 4;
    size_t off_ph = align4i(off);
    ushort* packHi = (ushort*)(wsi + off_ph); off = off_ph + 12800 / 2;
    ushort* packLo = (ushort*)(wsi + off);
    float* out    = (float*)d_out;

    int zb = (n + 1 + TPB - 1) / TPB;
    k_prep<<<zb + 7, TPB, 0, stream>>>(cnt, n + 1, zb, W1, packHi, packLo);
    k_fill<<<(E + TPB - 1) / TPB, TPB, 0, stream>>>(src, dst, cnt, bucket,
                                                    ovf_cnt, ovf_list, E);
    k_gather<<<(n + 3) / 4, TPB, 0, stream>>>(x, cnt, bucket, ovf_cnt, ovf_list,
                                              xs, invd, n);
    k_dense<<<DGRID, TPB, 0, stream>>>(xs, invd, packHi, packLo, b1, W2, p, n);
    k_out<<<(n + 3) / 4, TPB, 0, stream>>>(p, cnt, bucket, ovf_cnt, ovf_list,
                                           b2, out, n);
}